// Round 2
// baseline (500.734 us; speedup 1.0000x reference)
//
#include <hip/hip_runtime.h>
#include <math.h>

#define W_ 160
#define H_ 128
#define C_ 32
#define D_ 96
#define NPIX (H_*W_)          // 20480

// k_costpart tiling
#define TH 16
#define TW 32
#define HALO_H 18
#define HALO_W 34
#define HSTRIDE 35            // padded halo row stride (odd -> bank spread)
#define NHPTS (HALO_H*HSTRIDE) // 630
#define CC 16                 // channels per chunk (2 chunks)

// ---------------- workspace layout (floats) ----------------
// featT   : 3*H*W*C            = 1,966,080   @ 0
// part    : 3*D*H*W            = 5,898,240   @ 1,966,080
// wT      : 27*32              = 864         @ 7,864,320
// rotrans : 2*12               = 24          @ 7,865,184
#define OFF_FEATT   0
#define OFF_PART    1966080
#define OFF_WT      7864320
#define OFF_ROT     7865184

// ---------------------------------------------------------------------------
// Fused: blocks 0..239 transpose features (V,C,H,W) -> featT (V,H,W,C);
// block 240 does the tiny projection/weight prep.
__global__ __launch_bounds__(256) void k_prep_transpose(
    const float* __restrict__ f,
    const float* __restrict__ proj,
    const float* __restrict__ wsrc,
    float* __restrict__ fT,
    float* __restrict__ wT,
    float* __restrict__ rotrans)
{
    if (blockIdx.x < 240) {
        int t = blockIdx.x * 256 + threadIdx.x;  // t = v*20480 + y*160 + x
        int v = t / NPIX;
        const float* src = f + v * (C_*NPIX) + (t - v*NPIX);
        float o[32];
        #pragma unroll
        for (int c = 0; c < 32; ++c) o[c] = src[c * NPIX];
        float4* dst = (float4*)(fT + (size_t)t * 32);
        #pragma unroll
        for (int k = 0; k < 8; ++k) dst[k] = ((float4*)o)[k];
        return;
    }

    int t = threadIdx.x;
    // transpose weights [c][kd][kh][kw] -> [kd][kh][kw][c]
    for (int i = t; i < 864; i += 256) {
        int s = i >> 5, c = i & 31;          // s = (kd*3+kh)*3+kw
        wT[i] = wsrc[c * 27 + s];
    }
    if (t == 0) {
        float P[3][16];
        for (int v = 0; v < 3; ++v) {
            const float* E = proj + v * 32;        // (B=1, v, 0, :, :)
            const float* K = proj + v * 32 + 16;   // (B=1, v, 1, :, :)
            for (int i = 0; i < 3; ++i)
                for (int j = 0; j < 4; ++j)
                    P[v][i*4+j] = K[i*4+0]*E[0*4+j] + K[i*4+1]*E[1*4+j] + K[i*4+2]*E[2*4+j];
            for (int j = 0; j < 4; ++j) P[v][12+j] = E[12+j];
        }
        // general 4x4 inverse (cofactor)
        const float* m = P[0];
        float inv[16];
        inv[0]  =  m[5]*m[10]*m[15] - m[5]*m[11]*m[14] - m[9]*m[6]*m[15] + m[9]*m[7]*m[14] + m[13]*m[6]*m[11] - m[13]*m[7]*m[10];
        inv[4]  = -m[4]*m[10]*m[15] + m[4]*m[11]*m[14] + m[8]*m[6]*m[15] - m[8]*m[7]*m[14] - m[12]*m[6]*m[11] + m[12]*m[7]*m[10];
        inv[8]  =  m[4]*m[9]*m[15]  - m[4]*m[11]*m[13] - m[8]*m[5]*m[15] + m[8]*m[7]*m[13] + m[12]*m[5]*m[11] - m[12]*m[7]*m[9];
        inv[12] = -m[4]*m[9]*m[14]  + m[4]*m[10]*m[13] + m[8]*m[5]*m[14] - m[8]*m[6]*m[13] - m[12]*m[5]*m[10] + m[12]*m[6]*m[9];
        inv[1]  = -m[1]*m[10]*m[15] + m[1]*m[11]*m[14] + m[9]*m[2]*m[15] - m[9]*m[3]*m[14] - m[13]*m[2]*m[11] + m[13]*m[3]*m[10];
        inv[5]  =  m[0]*m[10]*m[15] - m[0]*m[11]*m[14] - m[8]*m[2]*m[15] + m[8]*m[3]*m[14] + m[12]*m[2]*m[11] - m[12]*m[3]*m[10];
        inv[9]  = -m[0]*m[9]*m[15]  + m[0]*m[11]*m[13] + m[8]*m[1]*m[15] - m[8]*m[3]*m[13] - m[12]*m[1]*m[11] + m[12]*m[3]*m[9];
        inv[13] =  m[0]*m[9]*m[14]  - m[0]*m[10]*m[13] - m[8]*m[1]*m[14] + m[8]*m[2]*m[13] + m[12]*m[1]*m[10] - m[12]*m[2]*m[9];
        inv[2]  =  m[1]*m[6]*m[15]  - m[1]*m[7]*m[14]  - m[5]*m[2]*m[15] + m[5]*m[3]*m[14] + m[13]*m[2]*m[7]  - m[13]*m[3]*m[6];
        inv[6]  = -m[0]*m[6]*m[15]  + m[0]*m[7]*m[14]  + m[4]*m[2]*m[15] - m[4]*m[3]*m[14] - m[12]*m[2]*m[7]  + m[12]*m[3]*m[6];
        inv[10] =  m[0]*m[5]*m[15]  - m[0]*m[7]*m[13]  - m[4]*m[1]*m[15] + m[4]*m[3]*m[13] + m[12]*m[1]*m[7]  - m[12]*m[3]*m[5];
        inv[14] = -m[0]*m[5]*m[14]  + m[0]*m[6]*m[13]  + m[4]*m[1]*m[14] - m[4]*m[2]*m[13] - m[12]*m[1]*m[6]  + m[12]*m[2]*m[5];
        inv[3]  = -m[1]*m[6]*m[11]  + m[1]*m[7]*m[10]  + m[5]*m[2]*m[11] - m[5]*m[3]*m[10] - m[9]*m[2]*m[7]   + m[9]*m[3]*m[6];
        inv[7]  =  m[0]*m[6]*m[11]  - m[0]*m[7]*m[10]  - m[4]*m[2]*m[11] + m[4]*m[3]*m[10] + m[8]*m[2]*m[7]   - m[8]*m[3]*m[6];
        inv[11] = -m[0]*m[5]*m[11]  + m[0]*m[7]*m[9]   + m[4]*m[1]*m[11] - m[4]*m[3]*m[9]  - m[8]*m[1]*m[7]   + m[8]*m[3]*m[5];
        inv[15] =  m[0]*m[5]*m[10]  - m[0]*m[6]*m[9]   - m[4]*m[1]*m[10] + m[4]*m[2]*m[9]  + m[8]*m[1]*m[6]   - m[8]*m[2]*m[5];
        float det = m[0]*inv[0] + m[1]*inv[4] + m[2]*inv[8] + m[3]*inv[12];
        float rdet = 1.0f / det;
        for (int i = 0; i < 16; ++i) inv[i] *= rdet;

        for (int v = 1; v < 3; ++v) {
            float M[16];
            for (int i = 0; i < 4; ++i)
                for (int j = 0; j < 4; ++j) {
                    float a = 0.f;
                    for (int k = 0; k < 4; ++k) a += P[v][i*4+k] * inv[k*4+j];
                    M[i*4+j] = a;
                }
            float* o = rotrans + (v-1)*12;
            for (int i = 0; i < 3; ++i) {
                for (int j = 0; j < 3; ++j) o[i*3+j] = M[i*4+j];
                o[9+i] = M[i*4+3];
            }
        }
    }
}

// ---------------------------------------------------------------------------
__global__ __launch_bounds__(256) void k_costpart(
    const float* __restrict__ featT,
    const float* __restrict__ rotrans_g,
    const float* __restrict__ wT,
    const float* __restrict__ dvals,
    float* __restrict__ part)
{
    __shared__ float4 sVar[NHPTS * 4];   // swizzled slot: p*4 + (c4 ^ ((p>>2)&3))
    __shared__ float4 sW4[216];          // [kd][kh][kw][c/4]
    __shared__ float  sRT[24];

    const int tid = threadIdx.x;
    const int bx = blockIdx.x, by = blockIdx.y, ds = blockIdx.z;

    for (int i = tid; i < 216; i += 256) sW4[i] = ((const float4*)wT)[i];
    if (tid < 24) sRT[tid] = rotrans_g[tid];
    const float dv = dvals[ds];

    const int ty = tid >> 4;             // 0..15
    const int tx = tid & 15;             // 0..15, each owns 2 consecutive x

    float acc[3][2] = {{0.f,0.f},{0.f,0.f},{0.f,0.f}};
    const float4* fp = (const float4*)featT;

    for (int chunk = 0; chunk < 2; ++chunk) {
        const int c0 = chunk * CC;
        __syncthreads();                  // protect LDS from previous conv reads
        // ---- fill variance halo tile (16 channels) ----
        for (int p = tid; p < NHPTS; p += 256) {
            const int py = p / HSTRIDE;
            const int px = p - py * HSTRIDE;
            const int gy = by * TH + py - 1;
            const int gx = bx * TW + px - 1;
            float4 var[4];
            if (gy < 0 || gy >= H_ || gx < 0 || gx >= W_) {
                #pragma unroll
                for (int c4 = 0; c4 < 4; ++c4) var[c4] = make_float4(0.f,0.f,0.f,0.f);
            } else {
                float4 s[4], q[4];
                const int rbase = ((gy * W_ + gx) * C_ + c0) >> 2;
                #pragma unroll
                for (int c4 = 0; c4 < 4; ++c4) {
                    float4 f = fp[rbase + c4];
                    s[c4] = f;
                    q[c4] = make_float4(f.x*f.x, f.y*f.y, f.z*f.z, f.w*f.w);
                }
                const float xf = (float)gx, yf = (float)gy;
                #pragma unroll
                for (int v = 0; v < 2; ++v) {
                    const float* rt = &sRT[v * 12];
                    float A0 = rt[0]*xf + rt[1]*yf + rt[2];
                    float A1 = rt[3]*xf + rt[4]*yf + rt[5];
                    float A2 = rt[6]*xf + rt[7]*yf + rt[8];
                    float X = A0 * dv + rt[9];
                    float Y = A1 * dv + rt[10];
                    float Z = A2 * dv + rt[11];
                    float rz = __builtin_amdgcn_rcpf(Z);   // ~1ulp fast rcp
                    float pxf = X * rz, pyf = Y * rz;
                    float x0f = floorf(pxf), y0f = floorf(pyf);
                    float fx = pxf - x0f, fy = pyf - y0f;
                    float w00 = (1.f-fx)*(1.f-fy), w10 = fx*(1.f-fy);
                    float w01 = (1.f-fx)*fy,       w11 = fx*fy;
                    float x1f = x0f + 1.f, y1f = y0f + 1.f;
                    bool vx0 = (x0f >= 0.f) && (x0f <= (float)(W_-1));
                    bool vx1 = (x1f >= 0.f) && (x1f <= (float)(W_-1));
                    bool vy0 = (y0f >= 0.f) && (y0f <= (float)(H_-1));
                    bool vy1 = (y1f >= 0.f) && (y1f <= (float)(H_-1));
                    w00 = (vx0 && vy0) ? w00 : 0.f;
                    w10 = (vx1 && vy0) ? w10 : 0.f;
                    w01 = (vx0 && vy1) ? w01 : 0.f;
                    w11 = (vx1 && vy1) ? w11 : 0.f;
                    int xc0 = (int)fminf(fmaxf(x0f, 0.f), (float)(W_-1));
                    int xc1 = (int)fminf(fmaxf(x1f, 0.f), (float)(W_-1));
                    int yc0 = (int)fminf(fmaxf(y0f, 0.f), (float)(H_-1));
                    int yc1 = (int)fminf(fmaxf(y1f, 0.f), (float)(H_-1));
                    const int vb = (v + 1) * H_;
                    int b00 = (((vb + yc0) * W_ + xc0) * C_ + c0) >> 2;
                    int b10 = (((vb + yc0) * W_ + xc1) * C_ + c0) >> 2;
                    int b01 = (((vb + yc1) * W_ + xc0) * C_ + c0) >> 2;
                    int b11 = (((vb + yc1) * W_ + xc1) * C_ + c0) >> 2;
                    #pragma unroll
                    for (int c4 = 0; c4 < 4; ++c4) {
                        float4 f00 = fp[b00 + c4], f10 = fp[b10 + c4];
                        float4 f01 = fp[b01 + c4], f11 = fp[b11 + c4];
                        float wx = w00*f00.x + w10*f10.x + w01*f01.x + w11*f11.x;
                        float wy = w00*f00.y + w10*f10.y + w01*f01.y + w11*f11.y;
                        float wz = w00*f00.z + w10*f10.z + w01*f01.z + w11*f11.z;
                        float ww = w00*f00.w + w10*f10.w + w01*f01.w + w11*f11.w;
                        s[c4].x += wx; s[c4].y += wy; s[c4].z += wz; s[c4].w += ww;
                        q[c4].x += wx*wx; q[c4].y += wy*wy; q[c4].z += wz*wz; q[c4].w += ww*ww;
                    }
                }
                const float inv3 = 1.f / 3.f;
                #pragma unroll
                for (int c4 = 0; c4 < 4; ++c4) {
                    float mx = s[c4].x * inv3, my = s[c4].y * inv3,
                          mz = s[c4].z * inv3, mw = s[c4].w * inv3;
                    var[c4] = make_float4(q[c4].x*inv3 - mx*mx, q[c4].y*inv3 - my*my,
                                          q[c4].z*inv3 - mz*mz, q[c4].w*inv3 - mw*mw);
                }
            }
            #pragma unroll
            for (int c4 = 0; c4 < 4; ++c4)
                sVar[(p << 2) + (c4 ^ ((p >> 2) & 3))] = var[c4];
        }
        __syncthreads();
        // ---- conv accumulate (3 kd planes, 2 outputs per thread) ----
        #pragma unroll
        for (int c4 = 0; c4 < 4; ++c4) {
            #pragma unroll
            for (int kh = 0; kh < 3; ++kh) {
                float4 wv[3][3];
                #pragma unroll
                for (int kd = 0; kd < 3; ++kd)
                    #pragma unroll
                    for (int kw = 0; kw < 3; ++kw)
                        wv[kd][kw] = sW4[((kd*3 + kh)*3 + kw) * 8 + chunk*4 + c4];
                float4 vv[4];
                const int rowb = (ty + kh) * HSTRIDE + tx * 2;
                #pragma unroll
                for (int i = 0; i < 4; ++i) {
                    int p = rowb + i;
                    vv[i] = sVar[(p << 2) + (c4 ^ ((p >> 2) & 3))];
                }
                #pragma unroll
                for (int kd = 0; kd < 3; ++kd)
                    #pragma unroll
                    for (int j = 0; j < 2; ++j)
                        #pragma unroll
                        for (int kw = 0; kw < 3; ++kw) {
                            float4 a = vv[kw + j];
                            float4 b = wv[kd][kw];
                            acc[kd][j] += a.x*b.x + a.y*b.y + a.z*b.z + a.w*b.w;
                        }
            }
        }
    }
    const int oy = by * TH + ty;
    const int ox = bx * TW + tx * 2;
    #pragma unroll
    for (int kd = 0; kd < 3; ++kd)
        #pragma unroll
        for (int j = 0; j < 2; ++j)
            part[(size_t)(kd * D_ + ds) * NPIX + oy * W_ + ox + j] = acc[kd][j];
}

// ---------------------------------------------------------------------------
__global__ __launch_bounds__(256) void k_softmax(
    const float* __restrict__ part,
    const float* __restrict__ dvals,
    const float* __restrict__ bias,
    float* __restrict__ out)
{
    __shared__ float sD[96];
    if (threadIdx.x < 96) sD[threadIdx.x] = dvals[threadIdx.x];
    __syncthreads();

    int pix = blockIdx.x * 256 + threadIdx.x;
    if (pix >= NPIX) return;
    float e[96];
    const float b = bias[0];
    float m = -1e30f;
    #pragma unroll
    for (int d = 0; d < 96; ++d) {
        float c = part[(size_t)(D_ + d) * NPIX + pix];              // kd=1 plane
        if (d > 0)  c += part[(size_t)(d - 1) * NPIX + pix];        // kd=0 plane
        if (d < 95) c += part[(size_t)(2*D_ + d + 1) * NPIX + pix]; // kd=2 plane
        c += b;
        e[d] = c;
        m = fmaxf(m, c);
    }
    float sum = 0.f, dsum = 0.f, isum = 0.f;
    #pragma unroll
    for (int d = 0; d < 96; ++d) {
        float ex = __expf(e[d] - m);
        e[d] = ex;
        sum  += ex;
        dsum += ex * sD[d];
        isum += ex * (float)d;
    }
    float inv = 1.f / sum;
    float depth = dsum * inv;
    float idxf = isum * inv;
    int di = (int)idxf;
    di = di < 0 ? 0 : (di > 95 ? 95 : di);
    float cs = 0.f;
    #pragma unroll
    for (int d = 0; d < 96; ++d) {
        bool in = (d >= di - 1) && (d <= di + 2);
        cs += in ? e[d] : 0.f;
    }
    out[pix] = depth;
    out[NPIX + pix] = cs * inv;
}

// ---------------------------------------------------------------------------
extern "C" void kernel_launch(void* const* d_in, const int* in_sizes, int n_in,
                              void* d_out, int out_size, void* d_ws, size_t ws_size,
                              hipStream_t stream)
{
    const float* features = (const float*)d_in[0];
    const float* proj     = (const float*)d_in[1];
    const float* dvals    = (const float*)d_in[2];
    const float* wsrc     = (const float*)d_in[3];
    const float* bias     = (const float*)d_in[4];
    float* ws = (float*)d_ws;
    float* featT   = ws + OFF_FEATT;
    float* part    = ws + OFF_PART;
    float* wT      = ws + OFF_WT;
    float* rotrans = ws + OFF_ROT;
    float* out = (float*)d_out;

    hipLaunchKernelGGL(k_prep_transpose, dim3(241), dim3(256), 0, stream,
                       features, proj, wsrc, featT, wT, rotrans);
    hipLaunchKernelGGL(k_costpart, dim3(5, 8, 96), dim3(256), 0, stream,
                       featT, rotrans, wT, dvals, part);
    hipLaunchKernelGGL(k_softmax, dim3(80), dim3(256), 0, stream, part, dvals, bias, out);
}